// Round 1
// baseline (281.032 us; speedup 1.0000x reference)
//
#include <hip/hip_runtime.h>
#include <hip/hip_bf16.h>

// Problem constants: B=8, S=2048, E=768, HEAD=128
#define BB 8
#define SS 2048
#define EE 768
#define HH 128
#define MM (BB*SS)   // 16384

typedef __attribute__((ext_vector_type(8))) short bf16x8;
typedef __attribute__((ext_vector_type(4))) float f32x4;

__device__ __forceinline__ unsigned short f2bf(float x) {
    unsigned int u = __float_as_uint(x);
    u += 0x7fff + ((u >> 16) & 1);   // RNE
    return (unsigned short)(u >> 16);
}

// ---------------------------------------------------------------------------
// Kernel 1: QKV projection.  C[m][n] = sum_k (X[m][k]*mask[m]) * W[n][k]
// A = masked X (fp32 global -> bf16 LDS inline), B^T = W ([128][768] row-major)
// Tile: 128(M) x 128(N), BK=64, 4 waves each 64x64 (4x4 MFMA 16x16x32 tiles).
// Writes: Q,K as [B*S][128] bf16 ; V transposed as [B][128][S] bf16.
// grid (128, 3), block 256
// ---------------------------------------------------------------------------
__global__ __launch_bounds__(256, 2)
void qkv_gemm(const float* __restrict__ X, const float* __restrict__ mask,
              const float* __restrict__ Wq, const float* __restrict__ Wk,
              const float* __restrict__ Wv,
              unsigned short* __restrict__ Q, unsigned short* __restrict__ K,
              unsigned short* __restrict__ Vt)
{
    const int m0  = blockIdx.x * 128;
    const int mat = blockIdx.y;
    const float* W = (mat == 0) ? Wq : ((mat == 1) ? Wk : Wv);

    __shared__ __align__(16) unsigned short As[128 * 64];  // [m][k] stride 64
    __shared__ __align__(16) unsigned short Bs[128 * 64];  // [n][k] stride 64

    const int t    = threadIdx.x;
    const int wave = t >> 6;
    const int lane = t & 63;
    const int quad = lane >> 4;
    const int l16  = lane & 15;
    const int wm   = (wave >> 1) * 64;
    const int wn   = (wave & 1) * 64;

    f32x4 acc[4][4];
#pragma unroll
    for (int i = 0; i < 4; i++)
#pragma unroll
        for (int j = 0; j < 4; j++) acc[i][j] = (f32x4)0.0f;

    for (int k0 = 0; k0 < EE; k0 += 64) {
        __syncthreads();
        // stage A: 128 rows x 64 cols fp32 -> bf16 (with mask)
#pragma unroll
        for (int it = 0; it < 8; it++) {
            int flat = it * 256 + t;          // 0..2047, 16 float4-chunks per row
            int row  = flat >> 4;
            int c4   = (flat & 15) * 4;
            const float4 xv = *(const float4*)(X + (size_t)(m0 + row) * EE + k0 + c4);
            float mk = mask[m0 + row];
            ushort4 o;
            o.x = f2bf(xv.x * mk); o.y = f2bf(xv.y * mk);
            o.z = f2bf(xv.z * mk); o.w = f2bf(xv.w * mk);
            *(ushort4*)&As[row * 64 + c4] = o;
        }
        // stage B: W rows 0..127, cols k0..k0+63
#pragma unroll
        for (int it = 0; it < 8; it++) {
            int flat = it * 256 + t;
            int row  = flat >> 4;
            int c4   = (flat & 15) * 4;
            const float4 wv = *(const float4*)(W + (size_t)row * EE + k0 + c4);
            ushort4 o;
            o.x = f2bf(wv.x); o.y = f2bf(wv.y);
            o.z = f2bf(wv.z); o.w = f2bf(wv.w);
            *(ushort4*)&Bs[row * 64 + c4] = o;
        }
        __syncthreads();
#pragma unroll
        for (int kk = 0; kk < 2; kk++) {
            bf16x8 a[4], b[4];
#pragma unroll
            for (int i = 0; i < 4; i++)
                a[i] = *(const bf16x8*)&As[(wm + i * 16 + l16) * 64 + kk * 32 + quad * 8];
#pragma unroll
            for (int j = 0; j < 4; j++)
                b[j] = *(const bf16x8*)&Bs[(wn + j * 16 + l16) * 64 + kk * 32 + quad * 8];
#pragma unroll
            for (int i = 0; i < 4; i++)
#pragma unroll
                for (int j = 0; j < 4; j++)
                    acc[i][j] = __builtin_amdgcn_mfma_f32_16x16x32_bf16(a[i], b[j], acc[i][j], 0, 0, 0);
        }
    }

    // epilogue: C/D layout row = quad*4 + r, col = l16  [measured: m89/m91]
#pragma unroll
    for (int i = 0; i < 4; i++) {
#pragma unroll
        for (int r = 0; r < 4; r++) {
            int m = m0 + wm + i * 16 + quad * 4 + r;
#pragma unroll
            for (int j = 0; j < 4; j++) {
                int n = wn + j * 16 + l16;
                unsigned short v = f2bf(acc[i][j][r]);
                if (mat == 0)      Q[(size_t)m * HH + n] = v;
                else if (mat == 1) K[(size_t)m * HH + n] = v;
                else {
                    int b = m >> 11;        // m / 2048 (tiles never straddle batches)
                    int s = m & 2047;
                    Vt[((size_t)b * HH + n) * SS + s] = v;
                }
            }
        }
    }
}

// ---------------------------------------------------------------------------
// Kernel 2: causal flash attention, D=128, Q-tile 64 rows, K-tile 64 tokens.
// 4 waves; wave w owns q-rows [w*16, w*16+16) for QK^T, softmax state, and PV
// (no cross-wave reduction; Ps region is wave-private -> no barrier P->PV).
// grid (32, 8), block 256
// ---------------------------------------------------------------------------
__global__ __launch_bounds__(256, 2)
void attn(const unsigned short* __restrict__ Q, const unsigned short* __restrict__ K,
          const unsigned short* __restrict__ Vt, float* __restrict__ Out)
{
    const int b  = blockIdx.y;
    const int q0 = blockIdx.x * 64;
    const int t    = threadIdx.x;
    const int wave = t >> 6;
    const int lane = t & 63;
    const int quad = lane >> 4;
    const int l16  = lane & 15;

    __shared__ __align__(16) unsigned short Ks[64 * 128];     // [token][d]
    __shared__ __align__(16) unsigned short Vs[128 * 64];     // [h][token]
    __shared__ __align__(16) unsigned short Ps[4][16 * 64];   // per-wave [row][token]

    // Q fragments in registers: A[m=l16][k=quad*8+j], rows q0+wave*16+l16
    bf16x8 qf[4];
    {
        const unsigned short* qrow = Q + (size_t)(b * SS + q0 + wave * 16 + l16) * HH;
#pragma unroll
        for (int dd = 0; dd < 4; dd++)
            qf[dd] = *(const bf16x8*)(qrow + dd * 32 + quad * 8);
    }

    f32x4 o[8];
#pragma unroll
    for (int j = 0; j < 8; j++) o[j] = (f32x4)0.0f;
    float mrow[4], lrow[4];
#pragma unroll
    for (int r = 0; r < 4; r++) { mrow[r] = -1e30f; lrow[r] = 0.0f; }

    // 1/sqrt(128) * log2(e): softmax in base-2 domain
    const float sscale = 0.08838834764831845f * 1.4426950408889634f;

    for (int k0 = 0; k0 <= q0; k0 += 64) {
        __syncthreads();   // protect K/V LDS from previous iteration's readers
        // stage K-tile: 64 x 128
#pragma unroll
        for (int it = 0; it < 4; it++) {
            int flat = it * 256 + t;
            int row  = flat >> 4;
            int c8   = (flat & 15) * 8;
            *(ulonglong2*)&Ks[row * 128 + c8] =
                *(const ulonglong2*)(K + (size_t)(b * SS + k0 + row) * HH + c8);
        }
        // stage V^T-tile: 128 x 64
#pragma unroll
        for (int it = 0; it < 4; it++) {
            int flat = it * 256 + t;
            int row  = flat >> 3;
            int c8   = (flat & 7) * 8;
            *(ulonglong2*)&Vs[row * 64 + c8] =
                *(const ulonglong2*)(Vt + ((size_t)b * HH + row) * SS + k0 + c8);
        }
        __syncthreads();

        // S = Q K^T : wave w -> rows w*16..+15, 4 col-tiles of 16 tokens
        f32x4 s[4];
#pragma unroll
        for (int ct = 0; ct < 4; ct++) s[ct] = (f32x4)0.0f;
#pragma unroll
        for (int dd = 0; dd < 4; dd++) {
#pragma unroll
            for (int ct = 0; ct < 4; ct++) {
                bf16x8 kfr = *(const bf16x8*)&Ks[(ct * 16 + l16) * 128 + dd * 32 + quad * 8];
                s[ct] = __builtin_amdgcn_mfma_f32_16x16x32_bf16(qf[dd], kfr, s[ct], 0, 0, 0);
            }
        }

        // scale + causal mask (only the diagonal tile k0==q0 needs masking)
        const bool diag = (k0 == q0);
        float sv[4][4];
#pragma unroll
        for (int ct = 0; ct < 4; ct++) {
            int col = k0 + ct * 16 + l16;
#pragma unroll
            for (int r = 0; r < 4; r++) {
                float v = s[ct][r] * sscale;
                if (diag) {
                    int row = q0 + wave * 16 + quad * 4 + r;
                    if (col > row) v = -1e30f;
                }
                sv[ct][r] = v;
            }
        }

        // online softmax: row r lives in regs r across 16 lanes of the quad
        float alpha[4];
#pragma unroll
        for (int r = 0; r < 4; r++) {
            float v = fmaxf(fmaxf(sv[0][r], sv[1][r]), fmaxf(sv[2][r], sv[3][r]));
            v = fmaxf(v, __shfl_xor(v, 1));
            v = fmaxf(v, __shfl_xor(v, 2));
            v = fmaxf(v, __shfl_xor(v, 4));
            v = fmaxf(v, __shfl_xor(v, 8));
            float mnew = fmaxf(mrow[r], v);
            alpha[r] = exp2f(mrow[r] - mnew);
            mrow[r]  = mnew;
        }
        float rsum[4];
#pragma unroll
        for (int r = 0; r < 4; r++) rsum[r] = 0.0f;
#pragma unroll
        for (int ct = 0; ct < 4; ct++) {
#pragma unroll
            for (int r = 0; r < 4; r++) {
                float p = exp2f(sv[ct][r] - mrow[r]);
                rsum[r] += p;
                Ps[wave][(quad * 4 + r) * 64 + ct * 16 + l16] = f2bf(p);
            }
        }
#pragma unroll
        for (int r = 0; r < 4; r++) {
            float v = rsum[r];
            v += __shfl_xor(v, 1);
            v += __shfl_xor(v, 2);
            v += __shfl_xor(v, 4);
            v += __shfl_xor(v, 8);
            lrow[r] = lrow[r] * alpha[r] + v;
        }
#pragma unroll
        for (int j = 0; j < 8; j++)
#pragma unroll
            for (int r = 0; r < 4; r++)
                o[j][r] *= alpha[r];

        // PV: A = P (wave-private LDS, A-layout), B = V via Vs[h][token]
#pragma unroll
        for (int kk = 0; kk < 2; kk++) {
            bf16x8 pf = *(const bf16x8*)&Ps[wave][l16 * 64 + kk * 32 + quad * 8];
#pragma unroll
            for (int j = 0; j < 8; j++) {
                bf16x8 vf = *(const bf16x8*)&Vs[(j * 16 + l16) * 64 + kk * 32 + quad * 8];
                o[j] = __builtin_amdgcn_mfma_f32_16x16x32_bf16(pf, vf, o[j], 0, 0, 0);
            }
        }
    }

    // epilogue: Out[b][q0+row][h] = o/l
#pragma unroll
    for (int r = 0; r < 4; r++) {
        float inv = 1.0f / lrow[r];
        size_t base = (size_t)(b * SS + q0 + wave * 16 + quad * 4 + r) * HH;
#pragma unroll
        for (int j = 0; j < 8; j++)
            Out[base + j * 16 + l16] = o[j][r] * inv;
    }
}

extern "C" void kernel_launch(void* const* d_in, const int* in_sizes, int n_in,
                              void* d_out, int out_size, void* d_ws, size_t ws_size,
                              hipStream_t stream) {
    const float* X    = (const float*)d_in[0];
    const float* mask = (const float*)d_in[1];
    const float* Wq   = (const float*)d_in[2];
    const float* Wk   = (const float*)d_in[3];
    const float* Wv   = (const float*)d_in[4];

    unsigned short* Q  = (unsigned short*)d_ws;                 // [16384][128] bf16, 4 MB
    unsigned short* K  = Q + (size_t)MM * HH;                   // 4 MB
    unsigned short* Vt = K + (size_t)MM * HH;                   // [8][128][2048] bf16, 4 MB

    qkv_gemm<<<dim3(MM / 128, 3), 256, 0, stream>>>(X, mask, Wq, Wk, Wv, Q, K, Vt);
    attn<<<dim3(SS / 64, BB), 256, 0, stream>>>(Q, K, Vt, (float*)d_out);
}

// Round 2
// 170.153 us; speedup vs baseline: 1.6516x; 1.6516x over previous
//
#include <hip/hip_runtime.h>
#include <hip/hip_bf16.h>

// Problem constants: B=8, S=2048, E=768, HEAD=128
#define BB 8
#define SS 2048
#define EE 768
#define HH 128
#define MM (BB*SS)   // 16384
#define NQT 32       // 64-row q-tiles per batch
#define KSPLIT 4

typedef __attribute__((ext_vector_type(8))) short bf16x8;
typedef __attribute__((ext_vector_type(4))) float f32x4;

__device__ __forceinline__ unsigned short f2bf(float x) {
    unsigned int u = __float_as_uint(x);
    u += 0x7fff + ((u >> 16) & 1);   // RNE
    return (unsigned short)(u >> 16);
}
__device__ __forceinline__ float bf2f(unsigned short h) {
    return __uint_as_float(((unsigned int)h) << 16);
}

// ---------------------------------------------------------------------------
// Prepass: W fp32 -> bf16, stacked [Wq;Wk;Wv] = [384][768]
// ---------------------------------------------------------------------------
__global__ void wcvt(const float* __restrict__ Wq, const float* __restrict__ Wk,
                     const float* __restrict__ Wv, unsigned short* __restrict__ Wb) {
    int i4 = (blockIdx.x * 256 + threadIdx.x) * 4;        // < 294912
    const float* src;
    int off;
    if (i4 < 98304)       { src = Wq; off = i4; }
    else if (i4 < 196608) { src = Wk; off = i4 - 98304; }
    else                  { src = Wv; off = i4 - 196608; }
    float4 v = *(const float4*)(src + off);
    ushort4 o;
    o.x = f2bf(v.x); o.y = f2bf(v.y); o.z = f2bf(v.z); o.w = f2bf(v.w);
    *(ushort4*)(Wb + i4) = o;
}

// ---------------------------------------------------------------------------
// Fused QKV GEMM: C[m][0:384] = (X[m]*mask[m]) . [Wq;Wk;Wv]^T  (X read ONCE)
// m-tile 32, N=384, BK=64, 4 waves: (wr=m-half of 16 rows, wc=n-half of 192)
// grid 512, block 256. LDS strides padded to 72 (=36 banks, 16B-aligned).
// ---------------------------------------------------------------------------
__global__ __launch_bounds__(256, 2)
void qkv_gemm(const float* __restrict__ X, const float* __restrict__ mask,
              const unsigned short* __restrict__ Wb,
              unsigned short* __restrict__ Q, unsigned short* __restrict__ K,
              unsigned short* __restrict__ Vt)
{
    const int m0 = blockIdx.x * 32;
    __shared__ __align__(16) unsigned short As[32 * 72];
    __shared__ __align__(16) unsigned short Bs[384 * 72];

    const int t = threadIdx.x, wave = t >> 6, lane = t & 63;
    const int quad = lane >> 4, l16 = lane & 15;
    const int wr = wave >> 1, wc = wave & 1;

    f32x4 acc[12];
#pragma unroll
    for (int ct = 0; ct < 12; ct++) acc[ct] = (f32x4)0.0f;

    for (int k0 = 0; k0 < EE; k0 += 64) {
        __syncthreads();
        // A: 32x64 fp32 -> bf16 (masked). 512 float4 chunks.
#pragma unroll
        for (int it = 0; it < 2; it++) {
            int flat = it * 256 + t;
            int row = flat >> 4, c4 = (flat & 15) * 4;
            float4 xv = *(const float4*)(X + (size_t)(m0 + row) * EE + k0 + c4);
            float mk = mask[m0 + row];
            ushort4 o;
            o.x = f2bf(xv.x * mk); o.y = f2bf(xv.y * mk);
            o.z = f2bf(xv.z * mk); o.w = f2bf(xv.w * mk);
            *(ushort4*)&As[row * 72 + c4] = o;
        }
        // B: 384x64 bf16 copy. 3072 8-short chunks.
#pragma unroll
        for (int it = 0; it < 12; it++) {
            int flat = it * 256 + t;
            int row = flat >> 3, c8 = (flat & 7) * 8;
            *(ulonglong2*)&Bs[row * 72 + c8] =
                *(const ulonglong2*)(Wb + (size_t)row * EE + k0 + c8);
        }
        __syncthreads();
#pragma unroll
        for (int kk = 0; kk < 2; kk++) {
            bf16x8 a = *(const bf16x8*)&As[(wr * 16 + l16) * 72 + kk * 32 + quad * 8];
#pragma unroll
            for (int ct = 0; ct < 12; ct++) {
                bf16x8 bfr = *(const bf16x8*)&Bs[(wc * 192 + ct * 16 + l16) * 72 + kk * 32 + quad * 8];
                acc[ct] = __builtin_amdgcn_mfma_f32_16x16x32_bf16(a, bfr, acc[ct], 0, 0, 0);
            }
        }
    }

    // epilogue: C/D row = quad*4+r, col = l16; route n -> Q / K / Vt
#pragma unroll
    for (int ct = 0; ct < 12; ct++) {
        int nb = wc * 192 + ct * 16;
#pragma unroll
        for (int r = 0; r < 4; r++) {
            int m = m0 + wr * 16 + quad * 4 + r;
            unsigned short v = f2bf(acc[ct][r]);
            int n = nb + l16;
            if (n < 128)      Q[(size_t)m * HH + n] = v;
            else if (n < 256) K[(size_t)m * HH + (n - 128)] = v;
            else {
                int b = m >> 11, s = m & 2047;
                Vt[((size_t)b * HH + (n - 256)) * SS + s] = v;
            }
        }
    }
}

// ---------------------------------------------------------------------------
// Flash attention with k-split: block = (qt, b, ks); processes k-tiles
// kt = ks, ks+4, ... <= qt. Writes partial (o bf16, m, l fp32).
// 4 waves of 16 q-rows. l accumulated via extra MFMA column (ones B-frag).
// Padded LDS strides: Ks 136, Vs/Ps 72 (both = 16B-aligned, ~conflict-free).
// ---------------------------------------------------------------------------
__global__ __launch_bounds__(256, 3)
void attn(const unsigned short* __restrict__ Q, const unsigned short* __restrict__ K,
          const unsigned short* __restrict__ Vt,
          unsigned short* __restrict__ Po, float* __restrict__ Pm, float* __restrict__ Pl)
{
    const int qt = blockIdx.x, b = blockIdx.y, ks = blockIdx.z;
    const int q0 = qt * 64;
    const int t = threadIdx.x, wave = t >> 6, lane = t & 63;
    const int quad = lane >> 4, l16 = lane & 15;

    __shared__ __align__(16) unsigned short Ks[64 * 136];
    __shared__ __align__(16) unsigned short Vs[128 * 72];
    __shared__ __align__(16) unsigned short Ps[4][16 * 72];

    bf16x8 qf[4];
    {
        const unsigned short* qrow = Q + (size_t)(b * SS + q0 + wave * 16 + l16) * HH;
#pragma unroll
        for (int dd = 0; dd < 4; dd++)
            qf[dd] = *(const bf16x8*)(qrow + dd * 32 + quad * 8);
    }

    f32x4 o[8];
#pragma unroll
    for (int j = 0; j < 8; j++) o[j] = (f32x4)0.0f;
    f32x4 o9 = (f32x4)0.0f;                     // row-sum accumulator (l)
    float mrow[4];
#pragma unroll
    for (int r = 0; r < 4; r++) mrow[r] = -1e30f;

    const float sscale = 0.08838834764831845f * 1.4426950408889634f;  // 1/sqrt(128)*log2e

    bf16x8 ones;
    {
        short e = (l16 == 0) ? (short)0x3F80 : (short)0;   // bf16 1.0 in column n=0
        ones = (bf16x8){e, e, e, e, e, e, e, e};
    }

    const int Nkt = qt + 1;
    for (int kt = ks; kt < Nkt; kt += KSPLIT) {
        const int k0 = kt * 64;
        __syncthreads();
        // stage K-tile 64x128
#pragma unroll
        for (int it = 0; it < 4; it++) {
            int flat = it * 256 + t;
            int row = flat >> 4, c8 = (flat & 15) * 8;
            *(ulonglong2*)&Ks[row * 136 + c8] =
                *(const ulonglong2*)(K + (size_t)(b * SS + k0 + row) * HH + c8);
        }
        // stage V^T-tile 128x64
#pragma unroll
        for (int it = 0; it < 4; it++) {
            int flat = it * 256 + t;
            int row = flat >> 3, c8 = (flat & 7) * 8;
            *(ulonglong2*)&Vs[row * 72 + c8] =
                *(const ulonglong2*)(Vt + ((size_t)b * HH + row) * SS + k0 + c8);
        }
        __syncthreads();

        // S = Q K^T
        f32x4 s[4];
#pragma unroll
        for (int ct = 0; ct < 4; ct++) s[ct] = (f32x4)0.0f;
#pragma unroll
        for (int dd = 0; dd < 4; dd++) {
#pragma unroll
            for (int ct = 0; ct < 4; ct++) {
                bf16x8 kfr = *(const bf16x8*)&Ks[(ct * 16 + l16) * 136 + dd * 32 + quad * 8];
                s[ct] = __builtin_amdgcn_mfma_f32_16x16x32_bf16(qf[dd], kfr, s[ct], 0, 0, 0);
            }
        }

        const bool diag = (kt == qt);
        float sv[4][4];
#pragma unroll
        for (int ct = 0; ct < 4; ct++) {
            int col = k0 + ct * 16 + l16;
#pragma unroll
            for (int r = 0; r < 4; r++) {
                float v = s[ct][r] * sscale;
                if (diag) {
                    int row = q0 + wave * 16 + quad * 4 + r;
                    if (col > row) v = -1e30f;
                }
                sv[ct][r] = v;
            }
        }

        // online max (16-lane butterfly per row)
        float alpha[4];
#pragma unroll
        for (int r = 0; r < 4; r++) {
            float v = fmaxf(fmaxf(sv[0][r], sv[1][r]), fmaxf(sv[2][r], sv[3][r]));
            v = fmaxf(v, __shfl_xor(v, 1));
            v = fmaxf(v, __shfl_xor(v, 2));
            v = fmaxf(v, __shfl_xor(v, 4));
            v = fmaxf(v, __shfl_xor(v, 8));
            float mnew = fmaxf(mrow[r], v);
            alpha[r] = exp2f(mrow[r] - mnew);
            mrow[r]  = mnew;
        }
        // P -> wave-private LDS (A-layout source)
#pragma unroll
        for (int ct = 0; ct < 4; ct++) {
#pragma unroll
            for (int r = 0; r < 4; r++) {
                float p = exp2f(sv[ct][r] - mrow[r]);
                Ps[wave][(quad * 4 + r) * 72 + ct * 16 + l16] = f2bf(p);
            }
        }
        // rescale accumulators
#pragma unroll
        for (int j = 0; j < 8; j++)
#pragma unroll
            for (int r = 0; r < 4; r++) o[j][r] *= alpha[r];
#pragma unroll
        for (int r = 0; r < 4; r++) o9[r] *= alpha[r];

        // PV (+ row-sum via ones column)
#pragma unroll
        for (int kk = 0; kk < 2; kk++) {
            bf16x8 pf = *(const bf16x8*)&Ps[wave][l16 * 72 + kk * 32 + quad * 8];
#pragma unroll
            for (int j = 0; j < 8; j++) {
                bf16x8 vf = *(const bf16x8*)&Vs[(j * 16 + l16) * 72 + kk * 32 + quad * 8];
                o[j] = __builtin_amdgcn_mfma_f32_16x16x32_bf16(pf, vf, o[j], 0, 0, 0);
            }
            o9 = __builtin_amdgcn_mfma_f32_16x16x32_bf16(pf, ones, o9, 0, 0, 0);
        }
    }

    // store partials (raw o, m, l)
    const size_t pb = ((size_t)b * NQT + qt) * KSPLIT + ks;
    const size_t pobase = pb * (64 * 128);
    const size_t mbase  = pb * 64;
#pragma unroll
    for (int r = 0; r < 4; r++) {
        int row = wave * 16 + quad * 4 + r;
        if (l16 == 0) { Pm[mbase + row] = mrow[r]; Pl[mbase + row] = o9[r]; }
#pragma unroll
        for (int j = 0; j < 8; j++)
            Po[pobase + (size_t)row * 128 + j * 16 + l16] = f2bf(o[j][r]);
    }
}

// ---------------------------------------------------------------------------
// Combine 4 k-split partials per (b, qt): out = sum(w*o) / sum(w*l)
// grid (32, 8), block 256: thread = (col, row-half)
// ---------------------------------------------------------------------------
__global__ __launch_bounds__(256)
void combine(const unsigned short* __restrict__ Po, const float* __restrict__ Pm,
             const float* __restrict__ Pl, float* __restrict__ Out)
{
    const int qt = blockIdx.x, b = blockIdx.y;
    const int t = threadIdx.x;
    const int col = t & 127, rh = t >> 7;
    const size_t pb0 = ((size_t)b * NQT + qt) * KSPLIT;

    for (int pass = 0; pass < 32; pass++) {
        int row = pass * 2 + rh;
        float m[KSPLIT], lv[KSPLIT];
#pragma unroll
        for (int s = 0; s < KSPLIT; s++) {
            m[s]  = Pm[(pb0 + s) * 64 + row];
            lv[s] = Pl[(pb0 + s) * 64 + row];
        }
        float ms = fmaxf(fmaxf(m[0], m[1]), fmaxf(m[2], m[3]));
        float l = 0.0f, acc = 0.0f;
#pragma unroll
        for (int s = 0; s < KSPLIT; s++) {
            float w = exp2f(m[s] - ms);
            l += w * lv[s];
            acc += w * bf2f(Po[(pb0 + s) * 8192 + (size_t)row * 128 + col]);
        }
        Out[((size_t)b * SS + qt * 64 + row) * HH + col] = acc / l;
    }
}

extern "C" void kernel_launch(void* const* d_in, const int* in_sizes, int n_in,
                              void* d_out, int out_size, void* d_ws, size_t ws_size,
                              hipStream_t stream) {
    const float* X    = (const float*)d_in[0];
    const float* mask = (const float*)d_in[1];
    const float* Wq   = (const float*)d_in[2];
    const float* Wk   = (const float*)d_in[3];
    const float* Wv   = (const float*)d_in[4];

    char* ws = (char*)d_ws;
    unsigned short* Wb = (unsigned short*)ws; ws += (size_t)384 * 768 * 2;     // 0.59 MB
    unsigned short* Q  = (unsigned short*)ws; ws += (size_t)MM * HH * 2;       // 4 MB
    unsigned short* Kb = (unsigned short*)ws; ws += (size_t)MM * HH * 2;       // 4 MB
    unsigned short* Vt = (unsigned short*)ws; ws += (size_t)MM * HH * 2;       // 4 MB
    unsigned short* Po = (unsigned short*)ws; ws += (size_t)BB * NQT * KSPLIT * 64 * 128 * 2; // 16 MB
    float* Pm = (float*)ws; ws += (size_t)BB * NQT * KSPLIT * 64 * 4;          // 0.25 MB
    float* Pl = (float*)ws;                                                    // 0.25 MB

    wcvt<<<288, 256, 0, stream>>>(Wq, Wk, Wv, Wb);
    qkv_gemm<<<512, 256, 0, stream>>>(X, mask, Wb, Q, Kb, Vt);
    attn<<<dim3(NQT, BB, KSPLIT), 256, 0, stream>>>(Q, Kb, Vt, Po, Pm, Pl);
    combine<<<dim3(NQT, BB), 256, 0, stream>>>(Po, Pm, Pl, (float*)d_out);
}